// Round 2
// baseline (369.169 us; speedup 1.0000x reference)
//
#include <hip/hip_runtime.h>
#include <stdint.h>

// Problem constants
#define NB       64
#define FIN      12
#define HD       64
#define NHEADS   4
#define DHEAD    16
#define NLAYERS  3
#define ODIM     128
#define LN_EPS   1e-5f
#define BTOT     8192

#define NTH      256
#define NW       (NLAYERS * 4)
#define WFRAG    4096  // u16 per packed weight
#define WIN_U16  2048  // packed W_in^T (zero-padded K=32)
#define NTILES   10    // band tiles (|tj-ti|<=1) of the 4x4 tile grid
#define MSK_U32  (NTILES * 64 * 2)   // 1280 u32 of f16 0/1 fragment masks

// Padded node-row stride: 20 u16 = 40 B = 10 dwords. Bank = (10m+2q) mod 32:
// 16 distinct row-banks, residual collisions <=2-way (free). 16-u16 stride was
// 8 dwords -> m,m+4 alias -> 4-way conflicts on every 8B op (3.5e7 cycles, r1).
#define STR      20
#define HSTR     (64 * STR)   // u16 per head region

typedef unsigned int       u32;
typedef unsigned short     u16;
typedef unsigned long long u64;
typedef _Float16           f16;

typedef f16    f16x8 __attribute__((ext_vector_type(8)));
typedef f16    f16x4 __attribute__((ext_vector_type(4)));
typedef f16    h2    __attribute__((ext_vector_type(2)));
typedef __fp16 hh2   __attribute__((ext_vector_type(2)));
typedef float  f32x4 __attribute__((ext_vector_type(4)));
union U128h { uint4 u; f16x8 v8; h2 v2[4]; };
union U64h  { uint2 u; f16x4 v4; h2 h[2]; u32 w[2]; u16 s[4]; };

#if __has_builtin(__builtin_amdgcn_exp2f)
  __device__ __forceinline__ float e2(float x) { return __builtin_amdgcn_exp2f(x); }
#else
  __device__ __forceinline__ float e2(float x) { return exp2f(x); }
#endif

__device__ __forceinline__ float fdot2h(h2 a, h2 b, float c) {
#if __has_builtin(__builtin_amdgcn_fdot2)
  return __builtin_amdgcn_fdot2(a, b, c, false);
#else
  return c + (float)a[0] * (float)b[0] + (float)a[1] * (float)b[1];
#endif
}

// pack two fp32 -> 2 fp16 in ONE inst (v_cvt_pkrtz_f16_f32). RTZ; verified
// absmax-neutral in an earlier round.
#if __has_builtin(__builtin_amdgcn_cvt_pkrtz)
__device__ __forceinline__ u32 packh2(float a, float b) {
  hh2 p = __builtin_amdgcn_cvt_pkrtz(a, b);
  return *(u32*)&p;
}
#else
__device__ __forceinline__ u32 packh2(float a, float b) {
  h2 p = {(f16)a, (f16)b};
  return *(u32*)&p;
}
#endif
__device__ __forceinline__ void wb4(u16* __restrict__ dst, f32x4 a) {
  *(uint2*)dst = make_uint2(packh2(a[0], a[1]), packh2(a[2], a[3]));
}

// K=16 MFMA; fall back to zero-padded K=32 (same k-slot semantics).
#if __has_builtin(__builtin_amdgcn_mfma_f32_16x16x16f16)
__device__ __forceinline__ f32x4 mfma16(f16x4 a, f16x4 b, f32x4 c) {
  return __builtin_amdgcn_mfma_f32_16x16x16f16(a, b, c, 0, 0, 0);
}
#elif __has_builtin(__builtin_amdgcn_mfma_f32_16x16x16_f16)
__device__ __forceinline__ f32x4 mfma16(f16x4 a, f16x4 b, f32x4 c) {
  return __builtin_amdgcn_mfma_f32_16x16x16_f16(a, b, c, 0, 0, 0);
}
#else
__device__ __forceinline__ f32x4 mfma16(f16x4 a, f16x4 b, f32x4 c) {
  f16x8 a8 = {a[0], a[1], a[2], a[3], (f16)0, (f16)0, (f16)0, (f16)0};
  f16x8 b8 = {b[0], b[1], b[2], b[3], (f16)0, (f16)0, (f16)0, (f16)0};
  return __builtin_amdgcn_mfma_f32_16x16x32_f16(a8, b8, c, 0, 0, 0);
}
#endif

// LDS: Q/K/V as [head][node][STR] f16 (10240 B each). Masks now live in
// registers (layer-invariant), no LDS copy. 30720 B total.
struct __align__(16) Smem {
  u16 Qh[NHEADS * HSTR];
  u16 Kh[NHEADS * HSTR];
  u16 Vh[NHEADS * HSTR];
};  // 30720 B

// ---------------- prep: pack weights in B-fragment order, W_in^T (K zero-padded
// to 32), and attention mask f16-fragments in S^T/P^T tile layout.
extern "C" __global__ void __launch_bounds__(256)
prep_pack(const float* __restrict__ Wq, const float* __restrict__ Wk,
          const float* __restrict__ Wv, const float* __restrict__ Wo,
          const float* __restrict__ W_in, const int* __restrict__ adj,
          u16* __restrict__ wsW) {
  const int w = blockIdx.x;
  if (w < NW) {
    const int l = w >> 2, ty = w & 3;
    const float* src = (ty == 0 ? Wq : ty == 1 ? Wk : ty == 2 ? Wv : Wo) + l * HD * HD;
    const float sc = (ty == 0) ? (0.25f * 1.44269504f) : 1.0f;
    u16* dst = wsW + w * WFRAG;
    for (int f = threadIdx.x; f < 512; f += 256) {
      const int lane = f & 63, kh = (f >> 6) & 1, nt = f >> 7;
      const int n  = nt * 16 + (lane & 15);
      const int k0 = kh * 32 + ((lane >> 4) & 3) * 8;
      u16 tmp[8];
      #pragma unroll
      for (int j = 0; j < 8; ++j) {
        f16 hv = (f16)(src[(k0 + j) * HD + n] * sc);
        tmp[j] = *(u16*)&hv;
      }
      *(uint4*)(dst + f * 8) = *(const uint4*)tmp;
    }
  } else if (w == NW) {
    const int t = threadIdx.x;
    const int mt = t >> 6, lane = t & 63;
    const int mm = lane & 15, qq = (lane >> 4) & 3;
    u16 tmp[8];
    #pragma unroll
    for (int j = 0; j < 8; ++j) {
      const int k = qq * 8 + j;
      f16 hv = (k < FIN) ? (f16)W_in[k * HD + mt * 16 + mm] : (f16)0.0f;
      tmp[j] = *(u16*)&hv;
    }
    *(uint4*)(wsW + NW * WFRAG + t * 8) = *(const uint4*)tmp;
  } else {
    // mask fragments: tile t=(ti,tj) band-ordered; element for lane l, pair pr:
    // i = ti*16 + (l&15), j = tj*16 + ((l>>4)&3)*4 + pr*2 + {0,1}
    static const int TIv[NTILES] = {0, 0, 1, 1, 1, 2, 2, 2, 3, 3};
    static const int TJv[NTILES] = {0, 1, 0, 1, 2, 1, 2, 3, 2, 3};
    u32* wsMsk = (u32*)(wsW + NW * WFRAG + WIN_U16);
    for (int idx = threadIdx.x; idx < MSK_U32; idx += 256) {
      const int tile = idx >> 7, rem = idx & 127;
      const int l = rem >> 1, pr = rem & 1;
      const int i  = TIv[tile] * 16 + (l & 15);
      const int j0 = TJv[tile] * 16 + ((l >> 4) & 3) * 4 + pr * 2;
      const u32 lo = (adj[i * NB + j0]     != 0) ? 0x3C00u : 0u;  // f16 1.0
      const u32 hi = (adj[i * NB + j0 + 1] != 0) ? 0x3C00u : 0u;
      wsMsk[idx] = lo | (hi << 16);
    }
  }
}

// Transposed GEMM: C^T = W^T @ H^T; A-frags = packed weights (global/L2),
// B-frags in registers. C^T: feat = mt*16 + q*4 + r, node = wv*16 + (lane&15).
__device__ __forceinline__ void mmT(const u16* __restrict__ wf, U128h b0, U128h b1,
                                    int lane, f32x4 acc[4]) {
  #pragma unroll
  for (int mt = 0; mt < 4; ++mt) {
    U128h a0, a1;
    a0.u = *(const uint4*)(wf + ((mt * 2 + 0) * 64 + lane) * 8);
    a1.u = *(const uint4*)(wf + ((mt * 2 + 1) * 64 + lane) * 8);
    acc[mt] = __builtin_amdgcn_mfma_f32_16x16x32_f16(a0.v8, b0.v8, acc[mt], 0, 0, 0);
    acc[mt] = __builtin_amdgcn_mfma_f32_16x16x32_f16(a1.v8, b1.v8, acc[mt], 0, 0, 0);
  }
}

// Build h B-fragments from hr registers via cross-lane shuffle (no LDS round-trip).
__device__ __forceinline__ void make_bfrags(const float hr[4][4], int q, int m,
                                            U128h& b0, U128h& b1) {
  u32 p[8];
  #pragma unroll
  for (int mt = 0; mt < 4; ++mt) {
    p[2 * mt]     = packh2(hr[mt][0], hr[mt][1]);
    p[2 * mt + 1] = packh2(hr[mt][2], hr[mt][3]);
  }
  const int sA = (2 * (q & 1)) * 16 + m;
  const int sB = sA + 16;
  u32 A[8], B[8];
  #pragma unroll
  for (int k = 0; k < 8; ++k) A[k] = (u32)__shfl((int)p[k], sA, 64);
  #pragma unroll
  for (int k = 0; k < 8; ++k) B[k] = (u32)__shfl((int)p[k], sB, 64);
  const bool hi = (q & 2) != 0;
  b0.u.x = hi ? A[2] : A[0];  b0.u.y = hi ? A[3] : A[1];
  b0.u.z = hi ? B[2] : B[0];  b0.u.w = hi ? B[3] : B[1];
  b1.u.x = hi ? A[6] : A[4];  b1.u.y = hi ? A[7] : A[5];
  b1.u.z = hi ? B[6] : B[4];  b1.u.w = hi ? B[7] : B[5];
}

extern "C" __global__ void __launch_bounds__(NTH, 5)
gnn_fused(const float* __restrict__ x, const float* __restrict__ b_in,
          const u16* __restrict__ wsW, const float* __restrict__ bo,
          const float* __restrict__ ln_g, const float* __restrict__ ln_b,
          const float* __restrict__ Wp1, const float* __restrict__ bp1,
          const float* __restrict__ Wp2, const float* __restrict__ bp2,
          float* __restrict__ out) {
  __shared__ Smem s;
  const int t    = threadIdx.x;
  const int lane = t & 63;
  const int wv   = t >> 6;
  const int eg   = (int)blockIdx.x;
  const int m    = lane & 15, q = lane >> 4;
  const int node = wv * 16 + m;

  const u16* wsWin = wsW + NW * WFRAG;

  // per-lane mask fragments in registers (layer-invariant; all indices below
  // are compile-time constants -> stays in VGPRs, no scratch)
  uint2 mskr[NTILES];
  {
    const u32* wsMsk = (const u32*)(wsWin + WIN_U16);
    #pragma unroll
    for (int i = 0; i < NTILES; ++i)
      mskr[i] = *(const uint2*)(wsMsk + i * 128 + (lane << 1));
  }

  // ---------------- phase 0: zero + stage x as f16 [node][32] in Kh region
  ((uint4*)s.Kh)[t] = make_uint4(0u, 0u, 0u, 0u);   // 4096 B staging region
  __syncthreads();
  if (t < (NB * FIN) / 4) {
    const int nd = t / 3, pos = (t % 3) * 4;
    const float4 v4 = *(const float4*)(x + eg * NB * FIN + t * 4);
    *(uint2*)&s.Kh[nd * 32 + pos] = make_uint2(packh2(v4.x, v4.y), packh2(v4.z, v4.w));
  }
  __syncthreads();

  // ---------------- input projection via MFMA: h^T = W_in^T @ x^T (K=32 padded)
  float hr[4][4];   // hr[mt][r]: h[node][feat = mt*16 + q*4 + r]
  {
    U128h xb;
    xb.u = *(const uint4*)&s.Kh[node * 32 + q * 8];
    #pragma unroll
    for (int mt = 0; mt < 4; ++mt) {
      U128h a0;
      a0.u = *(const uint4*)(wsWin + (mt * 64 + lane) * 8);
      f32x4 acc = {0.f, 0.f, 0.f, 0.f};
      acc = __builtin_amdgcn_mfma_f32_16x16x32_f16(a0.v8, xb.v8, acc, 0, 0, 0);
      const f32x4 b4 = *(const f32x4*)&b_in[mt * 16 + q * 4];
      #pragma unroll
      for (int r = 0; r < 4; ++r) hr[mt][r] = acc[r] + b4[r];
    }
  }
  __syncthreads();   // x staging dead; Kh free for k

  // ---------------- transformer layers
  for (int l = 0; l < NLAYERS; ++l) {
    const u16* wl = wsW + (l * 4) * WFRAG;

    // h B-fragments from registers (shuffle transpose), then fused q/k/v
    {
      U128h b0, b1;
      make_bfrags(hr, q, m, b0, b1);

      f32x4 aq[4] = {{0,0,0,0},{0,0,0,0},{0,0,0,0},{0,0,0,0}};
      mmT(wl + 0 * WFRAG, b0, b1, lane, aq);
      #pragma unroll
      for (int mt = 0; mt < 4; ++mt)
        wb4(&s.Qh[mt * HSTR + node * STR + q * 4], aq[mt]);

      f32x4 ak[4] = {{0,0,0,0},{0,0,0,0},{0,0,0,0},{0,0,0,0}};
      mmT(wl + 1 * WFRAG, b0, b1, lane, ak);
      #pragma unroll
      for (int mt = 0; mt < 4; ++mt)
        wb4(&s.Kh[mt * HSTR + node * STR + q * 4], ak[mt]);

      f32x4 av[4] = {{0,0,0,0},{0,0,0,0},{0,0,0,0},{0,0,0,0}};
      mmT(wl + 2 * WFRAG, b0, b1, lane, av);
      #pragma unroll
      for (int mt = 0; mt < 4; ++mt)
        wb4(&s.Vh[mt * HSTR + node * STR + q * 4], av[mt]);
    }
    __syncthreads();

    // ---- dense band-tile MFMA attention: wave = head hh.
    // S^T = K·Q^T (A=K-frag, B=Q-frag); S^T C-layout == P^T B-frag layout for
    // O^T = V^T·P^T. Mask as f16 0/1 pk_mul on packed P (regs); denom via
    // fdot2+shfl.
    {
      const int hh = wv;
      const u16* Qp = s.Qh + hh * HSTR;
      const u16* Kp = s.Kh + hh * HSTR;
      const u16* Vp = s.Vh + hh * HSTR;
      u16*       Op = s.Qh + hh * HSTR;   // O overwrites own Q region (safe)
      const h2 one2 = {(f16)1.0f, (f16)1.0f};
      const f32x4 z4 = {0.f, 0.f, 0.f, 0.f};

      f16x4 kf[4], vf[4];
      #pragma unroll
      for (int tj = 0; tj < 4; ++tj) {
        U64h tk; tk.u = *(const uint2*)&Kp[(tj * 16 + m) * STR + q * 4];
        kf[tj] = tk.v4;
      }
      #pragma unroll
      for (int kt = 0; kt < 4; ++kt) {
        const int j0 = kt * 16 + q * 4;   // V^T A-frag: strided u16 gather
        U64h tv;
        tv.s[0] = Vp[(j0 + 0) * STR + m];
        tv.s[1] = Vp[(j0 + 1) * STR + m];
        tv.s[2] = Vp[(j0 + 2) * STR + m];
        tv.s[3] = Vp[(j0 + 3) * STR + m];
        vf[kt] = tv.v4;
      }

#define ATTN_TI(TI, TJ0, NTJ, T0)                                              \
      {                                                                        \
        U64h tq; tq.u = *(const uint2*)&Qp[((TI) * 16 + m) * STR + q * 4];     \
        const f16x4 qf = tq.v4;                                                \
        f32x4 ot = z4;                                                         \
        float dsum = 0.0f;                                                     \
        _Pragma("unroll")                                                      \
        for (int dt = 0; dt < (NTJ); ++dt) {                                   \
          const int tj = (TJ0) + dt;                                           \
          f32x4 st = mfma16(kf[tj], qf, z4);                                   \
          const uint2 mmv = mskr[(T0) + dt];                                   \
          U64h pp;                                                             \
          pp.w[0] = packh2(e2(st[0]), e2(st[1]));                              \
          pp.w[1] = packh2(e2(st[2]), e2(st[3]));                              \
          pp.h[0] *= *(const h2*)&mmv.x;                                       \
          pp.h[1] *= *(const h2*)&mmv.y;                                       \
          dsum = fdot2h(pp.h[0], one2, dsum);                                  \
          dsum = fdot2h(pp.h[1], one2, dsum);                                  \
          ot = mfma16(vf[tj], pp.v4, ot);                                      \
        }                                                                      \
        dsum += __shfl_xor(dsum, 16, 64);                                      \
        dsum += __shfl_xor(dsum, 32, 64);                                      \
        const float rinv = 1.0f / dsum;                                        \
        ot[0] *= rinv; ot[1] *= rinv; ot[2] *= rinv; ot[3] *= rinv;            \
        wb4(&Op[((TI) * 16 + m) * STR + q * 4], ot);                           \
      }

      ATTN_TI(0, 0, 2, 0)
      ATTN_TI(1, 0, 3, 2)
      ATTN_TI(2, 1, 3, 5)
      ATTN_TI(3, 2, 2, 8)
#undef ATTN_TI
    }
    __syncthreads();

    // u = h + o @ Wo + bo (transposed GEMM, o B-frags from [head][node][STR]),
    // LN over q-lanes
    {
      const int hq = q >> 1, dof = (q & 1) * 8;
      const u16* ob0 = &s.Qh[hq * HSTR + node * STR + dof];
      const u16* ob1 = &s.Qh[(2 + hq) * HSTR + node * STR + dof];
      U128h b0, b1;
      const uint2 x0 = *(const uint2*)ob0, x1 = *(const uint2*)(ob0 + 4);
      const uint2 y0 = *(const uint2*)ob1, y1v = *(const uint2*)(ob1 + 4);
      b0.u = make_uint4(x0.x, x0.y, x1.x, x1.y);
      b1.u = make_uint4(y0.x, y0.y, y1v.x, y1v.y);
      f32x4 ao[4] = {{0,0,0,0},{0,0,0,0},{0,0,0,0},{0,0,0,0}};
      mmT(wl + 3 * WFRAG, b0, b1, lane, ao);

      float uu[4][4];
      float s1 = 0.0f, s2 = 0.0f;
      #pragma unroll
      for (int mt = 0; mt < 4; ++mt) {
        const f32x4 bo4 = *(const f32x4*)&bo[l * HD + mt * 16 + q * 4];
        #pragma unroll
        for (int r = 0; r < 4; ++r) {
          const float v = hr[mt][r] + ao[mt][r] + bo4[r];
          uu[mt][r] = v;
          s1 += v;
          s2 += v * v;
        }
      }
      s1 += __shfl_xor(s1, 16, 64); s1 += __shfl_xor(s1, 32, 64);
      s2 += __shfl_xor(s2, 16, 64); s2 += __shfl_xor(s2, 32, 64);
      const float mu  = s1 * (1.0f / 64.0f);
      const float var = s2 * (1.0f / 64.0f) - mu * mu;
      const float rs  = rsqrtf(var + LN_EPS);
      #pragma unroll
      for (int mt = 0; mt < 4; ++mt) {
        const f32x4 g4 = *(const f32x4*)&ln_g[l * HD + mt * 16 + q * 4];
        const f32x4 b4 = *(const f32x4*)&ln_b[l * HD + mt * 16 + q * 4];
        #pragma unroll
        for (int r = 0; r < 4; ++r)
          hr[mt][r] = (uu[mt][r] - mu) * rs * g4[r] + b4[r];
      }
    }
    if (l + 1 < NLAYERS) __syncthreads();   // protect o reads before next qkv writes
  }

  // ---------------- head: butterfly over node-lanes, pool in Kh alias, MLP
  float* pool = (float*)s.Kh;   // Kh dead (last read: layer-2 attention, barrier'd)
  float* y1   = pool + HD;
  __syncthreads();
  if (t < HD) pool[t] = 0.0f;
  __syncthreads();
  {
    #pragma unroll
    for (int mt = 0; mt < 4; ++mt)
      #pragma unroll
      for (int r = 0; r < 4; ++r) {
        float v = hr[mt][r];
        v += __shfl_xor(v, 1, 64); v += __shfl_xor(v, 2, 64);
        v += __shfl_xor(v, 4, 64); v += __shfl_xor(v, 8, 64);
        hr[mt][r] = v;
      }
    if (m == 0) {
      #pragma unroll
      for (int mt = 0; mt < 4; ++mt)
        #pragma unroll
        for (int r = 0; r < 4; ++r)
          atomicAdd(&pool[mt * 16 + q * 4 + r], hr[mt][r] * (1.0f / 64.0f));
    }
  }
  __syncthreads();
  if (t < HD) {
    float acc = bp1[t];
    #pragma unroll 8
    for (int k = 0; k < HD; ++k) acc = fmaf(pool[k], Wp1[k * HD + t], acc);
    y1[t] = fmaxf(acc, 0.0f);
  }
  __syncthreads();
  if (t < ODIM) {
    float acc = bp2[t];
    #pragma unroll 8
    for (int c = 0; c < HD; ++c) acc = fmaf(y1[c], Wp2[c * ODIM + t], acc);
    out[eg * ODIM + t] = acc;
  }
}

extern "C" void kernel_launch(void* const* d_in, const int* in_sizes, int n_in,
                              void* d_out, int out_size, void* d_ws, size_t ws_size,
                              hipStream_t stream) {
  const float* x    = (const float*)d_in[0];
  const int*   adj  = (const int*)d_in[1];
  const float* W_in = (const float*)d_in[2];
  const float* b_in = (const float*)d_in[3];
  const float* Wq   = (const float*)d_in[4];
  const float* Wk   = (const float*)d_in[5];
  const float* Wv   = (const float*)d_in[6];
  const float* Wo   = (const float*)d_in[7];
  const float* bo   = (const float*)d_in[8];
  const float* lng  = (const float*)d_in[9];
  const float* lnb  = (const float*)d_in[10];
  const float* Wp1  = (const float*)d_in[11];
  const float* bp1  = (const float*)d_in[12];
  const float* Wp2  = (const float*)d_in[13];
  const float* bp2  = (const float*)d_in[14];
  float* outp = (float*)d_out;
  u16*   wsW  = (u16*)d_ws;   // 12*4096 + 2048 u16 + 5120 B mask frags = ~105 KB

  hipLaunchKernelGGL(prep_pack, dim3(NW + 2), dim3(256), 0, stream,
                     Wq, Wk, Wv, Wo, W_in, adj, wsW);
  hipLaunchKernelGGL(gnn_fused, dim3(BTOT), dim3(NTH), 0, stream,
                     x, b_in, wsW, bo, lng, lnb, Wp1, bp1, Wp2, bp2, outp);
}

// Round 3
// 283.397 us; speedup vs baseline: 1.3027x; 1.3027x over previous
//
#include <hip/hip_runtime.h>
#include <stdint.h>

// Problem constants
#define NB       64
#define FIN      12
#define HD       64
#define NHEADS   4
#define DHEAD    16
#define NLAYERS  3
#define ODIM     128
#define LN_EPS   1e-5f
#define BTOT     8192

#define NTH      256
#define NW       (NLAYERS * 4)
#define WFRAG    4096  // u16 per packed weight
#define WIN_U16  2048  // packed W_in^T (zero-padded K=32)
#define NTILES   10    // band tiles (|tj-ti|<=1) of the 4x4 tile grid
#define MSK_U32  (NTILES * 64 * 2)   // 1280 u32 of f16 0/1 fragment masks

// Padded node-row stride: 20 u16 = 40 B = 10 dwords. Spreads the V-gather over
// all 32 banks (was 8 banks / 4-way at STR=16) and de-aliases the m/m+4 rows.
// r1->r2 evidence: SQ_LDS_BANK_CONFLICT 3.49e7 -> 3.47e6 with this padding.
#define STR      20
#define HSTR     (64 * STR)   // u16 per head region

typedef unsigned int       u32;
typedef unsigned short     u16;
typedef unsigned long long u64;
typedef _Float16           f16;

typedef f16    f16x8 __attribute__((ext_vector_type(8)));
typedef f16    f16x4 __attribute__((ext_vector_type(4)));
typedef f16    h2    __attribute__((ext_vector_type(2)));
typedef __fp16 hh2   __attribute__((ext_vector_type(2)));
typedef float  f32x4 __attribute__((ext_vector_type(4)));
union U128h { uint4 u; f16x8 v8; h2 v2[4]; };
union U64h  { uint2 u; f16x4 v4; h2 h[2]; u32 w[2]; u16 s[4]; };

#if __has_builtin(__builtin_amdgcn_exp2f)
  __device__ __forceinline__ float e2(float x) { return __builtin_amdgcn_exp2f(x); }
#else
  __device__ __forceinline__ float e2(float x) { return exp2f(x); }
#endif

__device__ __forceinline__ float fdot2h(h2 a, h2 b, float c) {
#if __has_builtin(__builtin_amdgcn_fdot2)
  return __builtin_amdgcn_fdot2(a, b, c, false);
#else
  return c + (float)a[0] * (float)b[0] + (float)a[1] * (float)b[1];
#endif
}

// pack two fp32 -> 2 fp16 in ONE inst (v_cvt_pkrtz_f16_f32). RTZ; verified
// absmax-neutral in an earlier round.
#if __has_builtin(__builtin_amdgcn_cvt_pkrtz)
__device__ __forceinline__ u32 packh2(float a, float b) {
  hh2 p = __builtin_amdgcn_cvt_pkrtz(a, b);
  return *(u32*)&p;
}
#else
__device__ __forceinline__ u32 packh2(float a, float b) {
  h2 p = {(f16)a, (f16)b};
  return *(u32*)&p;
}
#endif
__device__ __forceinline__ void wb4(u16* __restrict__ dst, f32x4 a) {
  *(uint2*)dst = make_uint2(packh2(a[0], a[1]), packh2(a[2], a[3]));
}

// K=16 MFMA; fall back to zero-padded K=32 (same k-slot semantics).
#if __has_builtin(__builtin_amdgcn_mfma_f32_16x16x16f16)
__device__ __forceinline__ f32x4 mfma16(f16x4 a, f16x4 b, f32x4 c) {
  return __builtin_amdgcn_mfma_f32_16x16x16f16(a, b, c, 0, 0, 0);
}
#elif __has_builtin(__builtin_amdgcn_mfma_f32_16x16x16_f16)
__device__ __forceinline__ f32x4 mfma16(f16x4 a, f16x4 b, f32x4 c) {
  return __builtin_amdgcn_mfma_f32_16x16x16_f16(a, b, c, 0, 0, 0);
}
#else
__device__ __forceinline__ f32x4 mfma16(f16x4 a, f16x4 b, f32x4 c) {
  f16x8 a8 = {a[0], a[1], a[2], a[3], (f16)0, (f16)0, (f16)0, (f16)0};
  f16x8 b8 = {b[0], b[1], b[2], b[3], (f16)0, (f16)0, (f16)0, (f16)0};
  return __builtin_amdgcn_mfma_f32_16x16x32_f16(a8, b8, c, 0, 0, 0);
}
#endif

// LDS: Q/K/V as [head][node][STR] f16 (10240 B each) + mask frags (5120 B).
// 35840 B -> 4 blocks/CU. Masks in LDS, NOT registers: r2 showed the register
// variant spills to scratch (FETCH 15.6->144 MB, WRITE 9.7->265 MB).
struct __align__(16) Smem {
  u16 Qh[NHEADS * HSTR];
  u16 Kh[NHEADS * HSTR];
  u16 Vh[NHEADS * HSTR];
  u32 Msk[MSK_U32];
};  // 35840 B

// ---------------- prep: pack weights in B-fragment order, W_in^T (K zero-padded
// to 32), and attention mask f16-fragments in S^T/P^T tile layout.
extern "C" __global__ void __launch_bounds__(256)
prep_pack(const float* __restrict__ Wq, const float* __restrict__ Wk,
          const float* __restrict__ Wv, const float* __restrict__ Wo,
          const float* __restrict__ W_in, const int* __restrict__ adj,
          u16* __restrict__ wsW) {
  const int w = blockIdx.x;
  if (w < NW) {
    const int l = w >> 2, ty = w & 3;
    const float* src = (ty == 0 ? Wq : ty == 1 ? Wk : ty == 2 ? Wv : Wo) + l * HD * HD;
    const float sc = (ty == 0) ? (0.25f * 1.44269504f) : 1.0f;
    u16* dst = wsW + w * WFRAG;
    for (int f = threadIdx.x; f < 512; f += 256) {
      const int lane = f & 63, kh = (f >> 6) & 1, nt = f >> 7;
      const int n  = nt * 16 + (lane & 15);
      const int k0 = kh * 32 + ((lane >> 4) & 3) * 8;
      u16 tmp[8];
      #pragma unroll
      for (int j = 0; j < 8; ++j) {
        f16 hv = (f16)(src[(k0 + j) * HD + n] * sc);
        tmp[j] = *(u16*)&hv;
      }
      *(uint4*)(dst + f * 8) = *(const uint4*)tmp;
    }
  } else if (w == NW) {
    const int t = threadIdx.x;
    const int mt = t >> 6, lane = t & 63;
    const int mm = lane & 15, qq = (lane >> 4) & 3;
    u16 tmp[8];
    #pragma unroll
    for (int j = 0; j < 8; ++j) {
      const int k = qq * 8 + j;
      f16 hv = (k < FIN) ? (f16)W_in[k * HD + mt * 16 + mm] : (f16)0.0f;
      tmp[j] = *(u16*)&hv;
    }
    *(uint4*)(wsW + NW * WFRAG + t * 8) = *(const uint4*)tmp;
  } else {
    // mask fragments: tile t=(ti,tj) band-ordered; element for lane l, pair pr:
    // i = ti*16 + (l&15), j = tj*16 + ((l>>4)&3)*4 + pr*2 + {0,1}
    static const int TIv[NTILES] = {0, 0, 1, 1, 1, 2, 2, 2, 3, 3};
    static const int TJv[NTILES] = {0, 1, 0, 1, 2, 1, 2, 3, 2, 3};
    u32* wsMsk = (u32*)(wsW + NW * WFRAG + WIN_U16);
    for (int idx = threadIdx.x; idx < MSK_U32; idx += 256) {
      const int tile = idx >> 7, rem = idx & 127;
      const int l = rem >> 1, pr = rem & 1;
      const int i  = TIv[tile] * 16 + (l & 15);
      const int j0 = TJv[tile] * 16 + ((l >> 4) & 3) * 4 + pr * 2;
      const u32 lo = (adj[i * NB + j0]     != 0) ? 0x3C00u : 0u;  // f16 1.0
      const u32 hi = (adj[i * NB + j0 + 1] != 0) ? 0x3C00u : 0u;
      wsMsk[idx] = lo | (hi << 16);
    }
  }
}

// Transposed GEMM: C^T = W^T @ H^T; A-frags = packed weights (global/L2),
// B-frags in registers. C^T: feat = mt*16 + q*4 + r, node = wv*16 + (lane&15).
__device__ __forceinline__ void mmT(const u16* __restrict__ wf, U128h b0, U128h b1,
                                    int lane, f32x4 acc[4]) {
  #pragma unroll
  for (int mt = 0; mt < 4; ++mt) {
    U128h a0, a1;
    a0.u = *(const uint4*)(wf + ((mt * 2 + 0) * 64 + lane) * 8);
    a1.u = *(const uint4*)(wf + ((mt * 2 + 1) * 64 + lane) * 8);
    acc[mt] = __builtin_amdgcn_mfma_f32_16x16x32_f16(a0.v8, b0.v8, acc[mt], 0, 0, 0);
    acc[mt] = __builtin_amdgcn_mfma_f32_16x16x32_f16(a1.v8, b1.v8, acc[mt], 0, 0, 0);
  }
}

// Build h B-fragments from hr registers via cross-lane shuffle (no LDS round-trip).
__device__ __forceinline__ void make_bfrags(const float hr[4][4], int q, int m,
                                            U128h& b0, U128h& b1) {
  u32 p[8];
  #pragma unroll
  for (int mt = 0; mt < 4; ++mt) {
    p[2 * mt]     = packh2(hr[mt][0], hr[mt][1]);
    p[2 * mt + 1] = packh2(hr[mt][2], hr[mt][3]);
  }
  const int sA = (2 * (q & 1)) * 16 + m;
  const int sB = sA + 16;
  u32 A[8], B[8];
  #pragma unroll
  for (int k = 0; k < 8; ++k) A[k] = (u32)__shfl((int)p[k], sA, 64);
  #pragma unroll
  for (int k = 0; k < 8; ++k) B[k] = (u32)__shfl((int)p[k], sB, 64);
  const bool hi = (q & 2) != 0;
  b0.u.x = hi ? A[2] : A[0];  b0.u.y = hi ? A[3] : A[1];
  b0.u.z = hi ? B[2] : B[0];  b0.u.w = hi ? B[3] : B[1];
  b1.u.x = hi ? A[6] : A[4];  b1.u.y = hi ? A[7] : A[5];
  b1.u.z = hi ? B[6] : B[4];  b1.u.w = hi ? B[7] : B[5];
}

extern "C" __global__ void __launch_bounds__(NTH, 4)
gnn_fused(const float* __restrict__ x, const float* __restrict__ b_in,
          const u16* __restrict__ wsW, const float* __restrict__ bo,
          const float* __restrict__ ln_g, const float* __restrict__ ln_b,
          const float* __restrict__ Wp1, const float* __restrict__ bp1,
          const float* __restrict__ Wp2, const float* __restrict__ bp2,
          float* __restrict__ out) {
  __shared__ Smem s;
  const int t    = threadIdx.x;
  const int lane = t & 63;
  const int wv   = t >> 6;
  const int eg   = (int)blockIdx.x;
  const int m    = lane & 15, q = lane >> 4;
  const int node = wv * 16 + m;

  const u16* wsWin = wsW + NW * WFRAG;

  // ---------------- phase 0: zero + stage x as f16 [node][32] in Kh region;
  // copy mask frags into LDS (layer-invariant, read 10x/wave/layer).
  ((uint4*)s.Kh)[t] = make_uint4(0u, 0u, 0u, 0u);   // 4096 B staging region
  {
    const uint4* mg4 = (const uint4*)(wsWin + WIN_U16);
    ((uint4*)s.Msk)[t] = mg4[t];
    if (t < 64) ((uint4*)s.Msk)[256 + t] = mg4[256 + t];
  }
  __syncthreads();
  if (t < (NB * FIN) / 4) {
    const int nd = t / 3, pos = (t % 3) * 4;
    const float4 v4 = *(const float4*)(x + eg * NB * FIN + t * 4);
    *(uint2*)&s.Kh[nd * 32 + pos] = make_uint2(packh2(v4.x, v4.y), packh2(v4.z, v4.w));
  }
  __syncthreads();

  // ---------------- input projection via MFMA: h^T = W_in^T @ x^T (K=32 padded)
  float hr[4][4];   // hr[mt][r]: h[node][feat = mt*16 + q*4 + r]
  {
    U128h xb;
    xb.u = *(const uint4*)&s.Kh[node * 32 + q * 8];
    #pragma unroll
    for (int mt = 0; mt < 4; ++mt) {
      U128h a0;
      a0.u = *(const uint4*)(wsWin + (mt * 64 + lane) * 8);
      f32x4 acc = {0.f, 0.f, 0.f, 0.f};
      acc = __builtin_amdgcn_mfma_f32_16x16x32_f16(a0.v8, xb.v8, acc, 0, 0, 0);
      const f32x4 b4 = *(const f32x4*)&b_in[mt * 16 + q * 4];
      #pragma unroll
      for (int r = 0; r < 4; ++r) hr[mt][r] = acc[r] + b4[r];
    }
  }
  __syncthreads();   // x staging dead; Kh free for k

  // ---------------- transformer layers
  for (int l = 0; l < NLAYERS; ++l) {
    const u16* wl = wsW + (l * 4) * WFRAG;

    // h B-fragments from registers (shuffle transpose), then fused q/k/v
    {
      U128h b0, b1;
      make_bfrags(hr, q, m, b0, b1);

      f32x4 aq[4] = {{0,0,0,0},{0,0,0,0},{0,0,0,0},{0,0,0,0}};
      mmT(wl + 0 * WFRAG, b0, b1, lane, aq);
      #pragma unroll
      for (int mt = 0; mt < 4; ++mt)
        wb4(&s.Qh[mt * HSTR + node * STR + q * 4], aq[mt]);

      f32x4 ak[4] = {{0,0,0,0},{0,0,0,0},{0,0,0,0},{0,0,0,0}};
      mmT(wl + 1 * WFRAG, b0, b1, lane, ak);
      #pragma unroll
      for (int mt = 0; mt < 4; ++mt)
        wb4(&s.Kh[mt * HSTR + node * STR + q * 4], ak[mt]);

      f32x4 av[4] = {{0,0,0,0},{0,0,0,0},{0,0,0,0},{0,0,0,0}};
      mmT(wl + 2 * WFRAG, b0, b1, lane, av);
      #pragma unroll
      for (int mt = 0; mt < 4; ++mt)
        wb4(&s.Vh[mt * HSTR + node * STR + q * 4], av[mt]);
    }
    __syncthreads();

    // ---- dense band-tile MFMA attention: wave = head hh.
    // S^T = K·Q^T (A=K-frag, B=Q-frag); S^T C-layout == P^T B-frag layout for
    // O^T = V^T·P^T. Mask as f16 0/1 pk_mul on packed P (LDS); denom via
    // fdot2+shfl.
    {
      const int hh = wv;
      const u16* Qp = s.Qh + hh * HSTR;
      const u16* Kp = s.Kh + hh * HSTR;
      const u16* Vp = s.Vh + hh * HSTR;
      u16*       Op = s.Qh + hh * HSTR;   // O overwrites own Q region (safe)
      const h2 one2 = {(f16)1.0f, (f16)1.0f};
      const f32x4 z4 = {0.f, 0.f, 0.f, 0.f};

      f16x4 kf[4], vf[4];
      #pragma unroll
      for (int tj = 0; tj < 4; ++tj) {
        U64h tk; tk.u = *(const uint2*)&Kp[(tj * 16 + m) * STR + q * 4];
        kf[tj] = tk.v4;
      }
      #pragma unroll
      for (int kt = 0; kt < 4; ++kt) {
        const int j0 = kt * 16 + q * 4;   // V^T A-frag: strided u16 gather
        U64h tv;
        tv.s[0] = Vp[(j0 + 0) * STR + m];
        tv.s[1] = Vp[(j0 + 1) * STR + m];
        tv.s[2] = Vp[(j0 + 2) * STR + m];
        tv.s[3] = Vp[(j0 + 3) * STR + m];
        vf[kt] = tv.v4;
      }

#define ATTN_TI(TI, TJ0, NTJ, T0)                                              \
      {                                                                        \
        U64h tq; tq.u = *(const uint2*)&Qp[((TI) * 16 + m) * STR + q * 4];     \
        const f16x4 qf = tq.v4;                                                \
        f32x4 ot = z4;                                                         \
        float dsum = 0.0f;                                                     \
        _Pragma("unroll")                                                      \
        for (int dt = 0; dt < (NTJ); ++dt) {                                   \
          const int tj = (TJ0) + dt;                                           \
          f32x4 st = mfma16(kf[tj], qf, z4);                                   \
          const uint2 mmv = *(const uint2*)&s.Msk[((T0) + dt) * 128 + (lane << 1)]; \
          U64h pp;                                                             \
          pp.w[0] = packh2(e2(st[0]), e2(st[1]));                              \
          pp.w[1] = packh2(e2(st[2]), e2(st[3]));                              \
          pp.h[0] *= *(const h2*)&mmv.x;                                       \
          pp.h[1] *= *(const h2*)&mmv.y;                                       \
          dsum = fdot2h(pp.h[0], one2, dsum);                                  \
          dsum = fdot2h(pp.h[1], one2, dsum);                                  \
          ot = mfma16(vf[tj], pp.v4, ot);                                      \
        }                                                                      \
        dsum += __shfl_xor(dsum, 16, 64);                                      \
        dsum += __shfl_xor(dsum, 32, 64);                                      \
        const float rinv = 1.0f / dsum;                                        \
        ot[0] *= rinv; ot[1] *= rinv; ot[2] *= rinv; ot[3] *= rinv;            \
        wb4(&Op[((TI) * 16 + m) * STR + q * 4], ot);                           \
      }

      ATTN_TI(0, 0, 2, 0)
      ATTN_TI(1, 0, 3, 2)
      ATTN_TI(2, 1, 3, 5)
      ATTN_TI(3, 2, 2, 8)
#undef ATTN_TI
    }
    __syncthreads();

    // u = h + o @ Wo + bo (transposed GEMM, o B-frags from [head][node][STR]),
    // LN over q-lanes
    {
      const int hq = q >> 1, dof = (q & 1) * 8;
      const u16* ob0 = &s.Qh[hq * HSTR + node * STR + dof];
      const u16* ob1 = &s.Qh[(2 + hq) * HSTR + node * STR + dof];
      U128h b0, b1;
      const uint2 x0 = *(const uint2*)ob0, x1 = *(const uint2*)(ob0 + 4);
      const uint2 y0 = *(const uint2*)ob1, y1v = *(const uint2*)(ob1 + 4);
      b0.u = make_uint4(x0.x, x0.y, x1.x, x1.y);
      b1.u = make_uint4(y0.x, y0.y, y1v.x, y1v.y);
      f32x4 ao[4] = {{0,0,0,0},{0,0,0,0},{0,0,0,0},{0,0,0,0}};
      mmT(wl + 3 * WFRAG, b0, b1, lane, ao);

      float uu[4][4];
      float s1 = 0.0f, s2 = 0.0f;
      #pragma unroll
      for (int mt = 0; mt < 4; ++mt) {
        const f32x4 bo4 = *(const f32x4*)&bo[l * HD + mt * 16 + q * 4];
        #pragma unroll
        for (int r = 0; r < 4; ++r) {
          const float v = hr[mt][r] + ao[mt][r] + bo4[r];
          uu[mt][r] = v;
          s1 += v;
          s2 += v * v;
        }
      }
      s1 += __shfl_xor(s1, 16, 64); s1 += __shfl_xor(s1, 32, 64);
      s2 += __shfl_xor(s2, 16, 64); s2 += __shfl_xor(s2, 32, 64);
      const float mu  = s1 * (1.0f / 64.0f);
      const float var = s2 * (1.0f / 64.0f) - mu * mu;
      const float rs  = rsqrtf(var + LN_EPS);
      #pragma unroll
      for (int mt = 0; mt < 4; ++mt) {
        const f32x4 g4 = *(const f32x4*)&ln_g[l * HD + mt * 16 + q * 4];
        const f32x4 b4 = *(const f32x4*)&ln_b[l * HD + mt * 16 + q * 4];
        #pragma unroll
        for (int r = 0; r < 4; ++r)
          hr[mt][r] = (uu[mt][r] - mu) * rs * g4[r] + b4[r];
      }
    }
    if (l + 1 < NLAYERS) __syncthreads();   // protect o reads before next qkv writes
  }

  // ---------------- head: butterfly over node-lanes, pool in Kh alias, MLP
  float* pool = (float*)s.Kh;   // Kh dead (last read: layer-2 attention, barrier'd)
  float* y1   = pool + HD;
  __syncthreads();
  if (t < HD) pool[t] = 0.0f;
  __syncthreads();
  {
    #pragma unroll
    for (int mt = 0; mt < 4; ++mt)
      #pragma unroll
      for (int r = 0; r < 4; ++r) {
        float v = hr[mt][r];
        v += __shfl_xor(v, 1, 64); v += __shfl_xor(v, 2, 64);
        v += __shfl_xor(v, 4, 64); v += __shfl_xor(v, 8, 64);
        hr[mt][r] = v;
      }
    if (m == 0) {
      #pragma unroll
      for (int mt = 0; mt < 4; ++mt)
        #pragma unroll
        for (int r = 0; r < 4; ++r)
          atomicAdd(&pool[mt * 16 + q * 4 + r], hr[mt][r] * (1.0f / 64.0f));
    }
  }
  __syncthreads();
  if (t < HD) {
    float acc = bp1[t];
    #pragma unroll 8
    for (int k = 0; k < HD; ++k) acc = fmaf(pool[k], Wp1[k * HD + t], acc);
    y1[t] = fmaxf(acc, 0.0f);
  }
  __syncthreads();
  if (t < ODIM) {
    float acc = bp2[t];
    #pragma unroll 8
    for (int c = 0; c < HD; ++c) acc = fmaf(y1[c], Wp2[c * ODIM + t], acc);
    out[eg * ODIM + t] = acc;
  }
}

extern "C" void kernel_launch(void* const* d_in, const int* in_sizes, int n_in,
                              void* d_out, int out_size, void* d_ws, size_t ws_size,
                              hipStream_t stream) {
  const float* x    = (const float*)d_in[0];
  const int*   adj  = (const int*)d_in[1];
  const float* W_in = (const float*)d_in[2];
  const float* b_in = (const float*)d_in[3];
  const float* Wq   = (const float*)d_in[4];
  const float* Wk   = (const float*)d_in[5];
  const float* Wv   = (const float*)d_in[6];
  const float* Wo   = (const float*)d_in[7];
  const float* bo   = (const float*)d_in[8];
  const float* lng  = (const float*)d_in[9];
  const float* lnb  = (const float*)d_in[10];
  const float* Wp1  = (const float*)d_in[11];
  const float* bp1  = (const float*)d_in[12];
  const float* Wp2  = (const float*)d_in[13];
  const float* bp2  = (const float*)d_in[14];
  float* outp = (float*)d_out;
  u16*   wsW  = (u16*)d_ws;   // 12*4096 + 2048 u16 + 5120 B mask frags = ~105 KB

  hipLaunchKernelGGL(prep_pack, dim3(NW + 2), dim3(256), 0, stream,
                     Wq, Wk, Wv, Wo, W_in, adj, wsW);
  hipLaunchKernelGGL(gnn_fused, dim3(BTOT), dim3(NTH), 0, stream,
                     x, b_in, wsW, bo, lng, lnb, Wp1, bp1, Wp2, bp2, outp);
}